// Round 13
// baseline (549.731 us; speedup 1.0000x reference)
//
#include <hip/hip_runtime.h>
#include <hip/hip_fp16.h>
#include <math.h>

// ---------------------------------------------------------------------------
// DHYPR hyperbolic GNN encoder, MI355X (gfx950).  Round 13:
//  - gather widened to 16 lanes/row x 8B/lane: one VMEM instruction now
//    fetches 4 rows (4 edges) -> 2x memory-level parallelism per wave vs
//    round 12's 2 rows/instr.  Quarter-select via cndmask tree on wave-
//    uniform records; quarter merge = 2 shfl_xor; float4 coalesced writes.
// Everything else unchanged from round 12.
// ---------------------------------------------------------------------------

constexpr double kMaxNorm = 1.0 - 1e-5;   // (1-PROJ_EPS)/sqrt(c), c=1
constexpr double kMinNorm = 1e-15;
#define kMaxNormF 0.99999f
#define kArtMaxF  6.1030338f
#define kOmMaxF   1.99999e-5f                    // 1 - kMaxNorm^2

typedef __attribute__((ext_vector_type(8))) short short8v;   // 8 bf16
typedef __attribute__((ext_vector_type(4))) float f32x4;

__device__ inline double wsum64(double v) {
#pragma unroll
  for (int o = 32; o > 0; o >>= 1) v += __shfl_xor(v, o, 64);
  return v;
}
__device__ inline float wsum32f(float v) {
#pragma unroll
  for (int o = 32; o > 0; o >>= 1) v += __shfl_xor(v, o, 64);
  return v;
}
__device__ inline float qsum16(float v) {   // reduce within 16-lane group
#pragma unroll
  for (int o = 1; o < 16; o <<= 1) v += __shfl_xor(v, o, 64);
  return v;
}
__device__ inline float tanh_pos(float z) {  // z >= 0, cancellation-free
  float e = __expf(-2.0f * z);
  return (1.0f - e) / (1.0f + e);
}

__device__ inline unsigned short f2bf(float f) {  // RN-even f32->bf16
  union { float f; unsigned int u; } v{f};
  unsigned int r = v.u + 0x7fffu + ((v.u >> 16) & 1u);
  return (unsigned short)(r >> 16);
}
__device__ inline float bf2f(unsigned short h) {
  union { unsigned int u; float f; } v{(unsigned int)h << 16};
  return v.f;
}

// ---- hb = proj(expmap0(bias)) ; outputs f32 (+ y2, 1-y2 scalars) -----------
__global__ __launch_bounds__(512) void k_bias(const float* __restrict__ b1,
                                              const float* __restrict__ b2,
                                              float* __restrict__ hb1,
                                              float* __restrict__ hb2,
                                              float* __restrict__ y21,
                                              float* __restrict__ y22,
                                              float* __restrict__ omy1,
                                              float* __restrict__ omy2) {
  int w = threadIdx.x >> 6, lane = threadIdx.x & 63;
  const float* bs = (w < 4) ? (b1 + w * 64) : (b2 + (w - 4) * 64);
  double v = (double)bs[lane];
  double un = fmax(sqrt(wsum64(v * v)), kMinNorm);
  double pn = tanh(un);
  double pf = pn > kMaxNorm ? kMaxNorm / pn : 1.0;
  double p = v * (pn / un) * pf;
  float* hb = (w < 4) ? hb1 + w * 64 : hb2 + (w - 4) * 64;
  hb[lane] = (float)p;
  if (lane == 0) {
    double n = pn * pf;
    int i = (w < 4) ? w : w - 4;
    float* y2 = (w < 4) ? y21 : y22;
    float* omy = (w < 4) ? omy1 : omy2;
    y2[i] = (float)(n * n);
    omy[i] = (float)(1.0 - n * n);
  }
}

// ---- weight prep: fragment-ready bf16 hi/lo, layout [s][b][f][lane][8] -----
__global__ __launch_bounds__(256) void k_wprep(const float* __restrict__ W,
                                               unsigned short* __restrict__ Wfh,
                                               unsigned short* __restrict__ Wfl,
                                               int DIN, int tot) {
  int idx = blockIdx.x * 256 + threadIdx.x;
  if (idx >= tot) return;
  int lane = idx & 63;
  int t = idx >> 6;
  int f = t & 3; t >>= 2;
  int ks = DIN >> 5;
  int s = t % ks;
  int b = t / ks;
  int c = f * 16 + (lane & 15);
  int k = s * 32 + (lane >> 4) * 8;
  const float* wp = W + ((size_t)(b * 64 + c)) * DIN + k;
  size_t dst = (((size_t)(s * 4 + b) * 4 + f) * 64 + lane) * 8;
#pragma unroll
  for (int j = 0; j < 8; ++j) {
    float v = wp[j];
    unsigned short h = f2bf(v);
    unsigned short l = f2bf(v - bf2f(h));
    Wfh[dst + j] = h;
    Wfl[dst + j] = l;
  }
}

// ---- shared epilogue: full Mobius tail for one row-chain -------------------
__device__ inline void tail_chain(float mx[4], float sart_row,
                                  const float hbv[4], float y2, float omy) {
  float p = mx[0] * mx[0] + mx[1] * mx[1] + mx[2] * mx[2] + mx[3] * mx[3];
  float mxn = fmaxf(sqrtf(qsum16(p)), 1e-30f);
  float z = mxn * sart_row;
  float e = __expf(-2.0f * z);
  float r1 = 1.0f / (1.0f + e);
  float nmv = (1.0f - e) * r1;
  float om = 4.0f * e * r1 * r1;
  float pf1 = nmv > kMaxNormF ? kMaxNormF / nmv : 1.0f;   // proj
  float nmvc = nmv * pf1;
  float x2 = nmvc * nmvc;
  float omx = (pf1 < 1.0f) ? kOmMaxF : om;                // 1 - x2, stable
  float mvs = nmvc / mxn;
  float pxy = 0.0f;
#pragma unroll
  for (int f = 0; f < 4; ++f) {
    mx[f] = mvs * mx[f];
    pxy += mx[f] * hbv[f];
  }
  float xy = qsum16(pxy);
  float A = 1.0f + 2.0f * xy + y2;
  float den = fmaxf(1.0f + 2.0f * xy + x2 * y2, 1e-15f);
  float rden = 1.0f / den;
  float hn2 = (x2 + 2.0f * xy + y2) * rden;
  float omh = omx * omy * rden;                           // 1 - hn^2
  float hn = fmaxf(sqrtf(fmaxf(hn2, 0.0f)), 1e-30f);
  float pf2 = 1.0f;
  if (hn > kMaxNormF) {                                   // proj
    pf2 = kMaxNormF / hn;
    hn = kMaxNormF;
    omh = kOmMaxF;
  }
  float art = 0.5f * __logf((1.0f + hn) * (1.0f + hn) / omh);
  float hts = (art / hn) * pf2 * rden;
#pragma unroll
  for (int f = 0; f < 4; ++f)
    mx[f] = hts * (A * mx[f] + omx * hbv[f]);
}

// ---- layer-1 GEMM + prescale + FUSED tail; block = 16 rows, wave = branch --
__global__ __launch_bounds__(256) void k_gemm1(const float* __restrict__ X,
                                               const unsigned short* __restrict__ Wfh,
                                               const unsigned short* __restrict__ Wfl,
                                               __half* __restrict__ C4,
                                               const float* __restrict__ hbAll,
                                               const float* __restrict__ y2All,
                                               const float* __restrict__ omyAll,
                                               int N) {
  const int bb = threadIdx.x >> 6, lane = threadIdx.x & 63;
  const int r0 = blockIdx.x * 16;
  const int l = lane & 15, g = lane >> 4;
  const int arow = min(r0 + l, N - 1);
  const int kbase = g * 8;
  f32x4 acc[4] = {};
  double ss = 0.0;
#pragma unroll
  for (int s = 0; s < 8; ++s) {
    const float* ap = X + (size_t)arow * 256 + s * 32 + kbase;
    const float4 a0 = *reinterpret_cast<const float4*>(ap);
    const float4 a1 = *reinterpret_cast<const float4*>(ap + 4);
    float av[8] = {a0.x, a0.y, a0.z, a0.w, a1.x, a1.y, a1.z, a1.w};
    short8v ah, al;
#pragma unroll
    for (int j = 0; j < 8; ++j) {
      ss += (double)av[j] * av[j];
      unsigned short h = f2bf(av[j]);
      ah[j] = (short)h;
      al[j] = (short)f2bf(av[j] - bf2f(h));
    }
#pragma unroll
    for (int f = 0; f < 4; ++f) {
      size_t wi = (((size_t)(s * 4 + bb) * 4 + f) * 64 + lane) * 8;
      short8v bh = *reinterpret_cast<const short8v*>(Wfh + wi);
      short8v bl = *reinterpret_cast<const short8v*>(Wfl + wi);
      acc[f] = __builtin_amdgcn_mfma_f32_16x16x32_bf16(ah, bl, acc[f], 0, 0, 0);
      acc[f] = __builtin_amdgcn_mfma_f32_16x16x32_bf16(al, bh, acc[f], 0, 0, 0);
      acc[f] = __builtin_amdgcn_mfma_f32_16x16x32_bf16(ah, bh, acc[f], 0, 0, 0);
    }
  }
  // prescale for input row r0+l (expmap0(x) scale + artanh factor)
  ss += __shfl_xor(ss, 16, 64);
  ss += __shfl_xor(ss, 32, 64);
  float un = fmaxf(sqrtf((float)ss), 1e-30f);
  float pn = tanh_pos(un);
  float pfx = pn > kMaxNormF ? kMaxNormF / pn : 1.0f;
  float xn = fmaxf(pn * pfx, 1e-30f);
  float s_i = (pn / un) * pfx;
  float sart_i = fminf(un, kArtMaxF) / xn;   // artanh(xn)/xn exactly
  float hbv[4];
  float y2v = y2All[bb], omyv = omyAll[bb];
#pragma unroll
  for (int f = 0; f < 4; ++f) hbv[f] = hbAll[bb * 64 + f * 16 + l];
#pragma unroll
  for (int j = 0; j < 4; ++j) {
    int row = r0 + g * 4 + j;
    float s_row = __shfl(s_i, g * 4 + j, 64);
    float sart_row = __shfl(sart_i, g * 4 + j, 64);
    float mx[4] = {s_row * acc[0][j], s_row * acc[1][j], s_row * acc[2][j],
                   s_row * acc[3][j]};
    tail_chain(mx, sart_row, hbv, y2v, omyv);
    if (row < N) {
      size_t base = ((size_t)bb * N + row) * 64 + l;
      C4[base] = __float2half(mx[0]);
      C4[base + 16] = __float2half(mx[1]);
      C4[base + 32] = __float2half(mx[2]);
      C4[base + 48] = __float2half(mx[3]);
    }
  }
}

// ---- layer-2 GEMM + FUSED tail: per-branch (blockIdx.y), DIN=64 ------------
__global__ __launch_bounds__(256) void k_gemm2(const float* __restrict__ X4,
                                               const unsigned short* __restrict__ Wfh,
                                               const unsigned short* __restrict__ Wfl,
                                               __half* __restrict__ C4,
                                               const float* __restrict__ auxT4,
                                               const float* __restrict__ hbAll,
                                               const float* __restrict__ y2All,
                                               const float* __restrict__ omyAll,
                                               int N) {
  const int wave = threadIdx.x >> 6, lane = threadIdx.x & 63;
  const int b = blockIdx.y;
  const int r0 = blockIdx.x * 64 + wave * 16;
  const int l = lane & 15, g = lane >> 4;
  const int arow = min(r0 + l, N - 1);
  const int kbase = g * 8;
  const float* X = X4 + (size_t)b * N * 64;
  f32x4 acc[4] = {};
#pragma unroll
  for (int s = 0; s < 2; ++s) {
    const float* ap = X + (size_t)arow * 64 + s * 32 + kbase;
    const float4 a0 = *reinterpret_cast<const float4*>(ap);
    const float4 a1 = *reinterpret_cast<const float4*>(ap + 4);
    float av[8] = {a0.x, a0.y, a0.z, a0.w, a1.x, a1.y, a1.z, a1.w};
    short8v ah, al;
#pragma unroll
    for (int j = 0; j < 8; ++j) {
      unsigned short h = f2bf(av[j]);
      ah[j] = (short)h;
      al[j] = (short)f2bf(av[j] - bf2f(h));
    }
#pragma unroll
    for (int f = 0; f < 4; ++f) {
      size_t wi = (((size_t)(s * 4 + b) * 4 + f) * 64 + lane) * 8;
      short8v bh = *reinterpret_cast<const short8v*>(Wfh + wi);
      short8v bl = *reinterpret_cast<const short8v*>(Wfl + wi);
      acc[f] = __builtin_amdgcn_mfma_f32_16x16x32_bf16(ah, bl, acc[f], 0, 0, 0);
      acc[f] = __builtin_amdgcn_mfma_f32_16x16x32_bf16(al, bh, acc[f], 0, 0, 0);
      acc[f] = __builtin_amdgcn_mfma_f32_16x16x32_bf16(ah, bh, acc[f], 0, 0, 0);
    }
  }
  float atn = auxT4[(size_t)b * N + arow];
  float xn = fmaxf(tanh_pos(atn), 1e-30f);
  float sart_i = atn / xn;
  float hbv[4];
  float y2v = y2All[b], omyv = omyAll[b];
#pragma unroll
  for (int f = 0; f < 4; ++f) hbv[f] = hbAll[b * 64 + f * 16 + l];
#pragma unroll
  for (int j = 0; j < 4; ++j) {
    int row = r0 + g * 4 + j;
    float sart_row = __shfl(sart_i, g * 4 + j, 64);
    float mx[4] = {acc[0][j], acc[1][j], acc[2][j], acc[3][j]};
    tail_chain(mx, sart_row, hbv, y2v, omyv);
    if (row < N) {
      size_t base = ((size_t)b * N + row) * 64 + l;
      C4[base] = __float2half(mx[0]);
      C4[base + 16] = __float2half(mx[1]);
      C4[base + 32] = __float2half(mx[2]);
      C4[base + 48] = __float2half(mx[3]);
    }
  }
}

// ===================== CSR build: bucketed counting sort ====================
__global__ __launch_bounds__(512) void k_bhist(const int* __restrict__ dst,
                                               int* __restrict__ bcnt, int E,
                                               int nbuck) {
  __shared__ int lcnt[512];
  int tid = threadIdx.x;
  for (int k = tid; k < nbuck; k += 512) lcnt[k] = 0;
  __syncthreads();
  int b = blockIdx.y;
  int e0 = blockIdx.x * 8192;
  const int* db = dst + (size_t)b * E;
#pragma unroll
  for (int i = 0; i < 16; ++i) {
    int e = e0 + i * 512 + tid;
    if (e < E) atomicAdd(&lcnt[db[e] >> 7], 1);
  }
  __syncthreads();
  for (int k = tid; k < nbuck; k += 512) {
    int c = lcnt[k];
    if (c) atomicAdd(&bcnt[b * nbuck + k], c);
  }
}

__global__ __launch_bounds__(256) void k_bscan(const int* __restrict__ bcnt,
                                               int* __restrict__ boff,
                                               int* __restrict__ bcur,
                                               int* __restrict__ rp4, int TB,
                                               int n4, int Etot) {
  __shared__ int wsums[4];
  int t = threadIdx.x;
  int lane = t & 63, wv = t >> 6;
  int vals[8];
  int s = 0;
#pragma unroll
  for (int i = 0; i < 8; ++i) {
    int idx = t * 8 + i;
    int v = (idx < TB) ? bcnt[idx] : 0;
    vals[i] = s;
    s += v;
  }
  int incl = s;
#pragma unroll
  for (int o = 1; o < 64; o <<= 1) {
    int u = __shfl_up(incl, o, 64);
    if (lane >= o) incl += u;
  }
  if (lane == 63) wsums[wv] = incl;
  __syncthreads();
  int woff = 0;
  for (int i = 0; i < wv; ++i) woff += wsums[i];
  int texcl = woff + incl - s;
#pragma unroll
  for (int i = 0; i < 8; ++i) {
    int idx = t * 8 + i;
    if (idx < TB) {
      int o = texcl + vals[i];
      boff[idx] = o;
      bcur[idx] = o;
    }
  }
  if (t == 0) {
    boff[TB] = Etot;
    rp4[n4] = Etot;
  }
}

__global__ __launch_bounds__(512) void k_bpart(const int* __restrict__ src,
                                               const int* __restrict__ dst,
                                               const float* __restrict__ val,
                                               int* __restrict__ bcur,
                                               int2* __restrict__ ebuf, int E,
                                               int nbuck) {
  __shared__ int lcnt[512];
  __shared__ int lbase[512];
  int tid = threadIdx.x;
  for (int k = tid; k < nbuck; k += 512) lcnt[k] = 0;
  __syncthreads();
  int b = blockIdx.y;
  int e0 = blockIdx.x * 8192;
  const int* db = dst + (size_t)b * E;
  const int* sb = src + (size_t)b * E;
  const float* vb = val + (size_t)b * E;
#pragma unroll
  for (int i = 0; i < 16; ++i) {
    int e = e0 + i * 512 + tid;
    if (e < E) atomicAdd(&lcnt[db[e] >> 7], 1);
  }
  __syncthreads();
  for (int k = tid; k < nbuck; k += 512) {
    int c = lcnt[k];
    lbase[k] = c ? atomicAdd(&bcur[b * nbuck + k], c) : 0;
  }
  __syncthreads();
  for (int k = tid; k < nbuck; k += 512) lcnt[k] = 0;
  __syncthreads();
#pragma unroll
  for (int i = 0; i < 16; ++i) {
    int e = e0 + i * 512 + tid;
    if (e < E) {
      int d = db[e];
      int bk = d >> 7;
      int r = atomicAdd(&lcnt[bk], 1);
      int2 ev;
      ev.x = ((d & 127) << 17) | sb[e];
      ev.y = __float_as_int(vb[e]);
      ebuf[(size_t)lbase[bk] + r] = ev;
    }
  }
}

__global__ __launch_bounds__(256) void k_bfine(const int2* __restrict__ ebuf,
                                               const int* __restrict__ boff,
                                               int* __restrict__ rp4,
                                               int2* __restrict__ pvedge,
                                               int N, int nbuck) {
  __shared__ int ncnt[128], noff[128], ncur[128];
  __shared__ int w0tot;
  int tid = threadIdx.x;
  int br = blockIdx.y, bk = blockIdx.x;
  int idx = br * nbuck + bk;
  int ebeg = boff[idx], eend = boff[idx + 1];
  int n0 = bk << 7;
  int nn = min(128, N - n0);
  if (tid < 128) ncnt[tid] = 0;
  __syncthreads();
  for (int j = ebeg + tid; j < eend; j += 256)
    atomicAdd(&ncnt[ebuf[j].x >> 17], 1);
  __syncthreads();
  int v = (tid < 128) ? ncnt[tid] : 0;
  int lane = tid & 63;
  int incl = v;
#pragma unroll
  for (int o = 1; o < 64; o <<= 1) {
    int u = __shfl_up(incl, o, 64);
    if (lane >= o) incl += u;
  }
  if (tid == 63) w0tot = incl;
  __syncthreads();
  if (tid >= 64 && tid < 128) incl += w0tot;
  if (tid < 128) {
    noff[tid] = incl - v;
    ncur[tid] = incl - v;
  }
  __syncthreads();
  if (tid < nn) rp4[(size_t)br * N + n0 + tid] = ebeg + noff[tid];
  for (int j = ebeg + tid; j < eend; j += 256) {
    int2 ev = ebuf[j];
    int dl = ev.x >> 17;
    int pos = ebeg + atomicAdd(&ncur[dl], 1);
    // .x = src*128: byte offset of the f16 row (row = 64 halves = 128 B)
    pvedge[pos] = make_int2((ev.x & 0x1FFFF) << 7, ev.y);
  }
}

// ---- quad f16 gather: 16 lanes/row x 8B, 4 edges per VMEM instruction ------
// Lane (q = lane>>4, d = lane&15) handles edge 4k+q, dims 4d..4d+3.
// Returns merged per-lane dims (4d..4d+3), replicated across quarters.
__device__ inline void gather_row_q4(const char* __restrict__ htb,
                                     const int2* __restrict__ pvedge, int beg,
                                     int end, int q, int d, float a[4]) {
  a[0] = a[1] = a[2] = a[3] = 0.0f;
  const unsigned dOff = (unsigned)d * 8u;
  int j = beg;
  for (; j + 16 <= end; j += 16) {
    int2 e[16];
#pragma unroll
    for (int k = 0; k < 16; ++k) e[k] = pvedge[j + k];
#pragma unroll
    for (int k = 0; k < 4; ++k) {
      int ex = (q == 0) ? e[4 * k].x
                        : (q == 1) ? e[4 * k + 1].x
                                   : (q == 2) ? e[4 * k + 2].x : e[4 * k + 3].x;
      int ey = (q == 0) ? e[4 * k].y
                        : (q == 1) ? e[4 * k + 1].y
                                   : (q == 2) ? e[4 * k + 2].y : e[4 * k + 3].y;
      const __half2* p =
          reinterpret_cast<const __half2*>(htb + ((unsigned)ex + dOff));
      __half2 h0 = p[0], h1 = p[1];
      float v = __int_as_float(ey);
      a[0] = fmaf(v, __half2float(__low2half(h0)), a[0]);
      a[1] = fmaf(v, __half2float(__high2half(h0)), a[1]);
      a[2] = fmaf(v, __half2float(__low2half(h1)), a[2]);
      a[3] = fmaf(v, __half2float(__high2half(h1)), a[3]);
    }
  }
  if (j < end) {  // clamped+masked final chunk (dummy gathers hit last row)
    int last = end - 1;
    int2 e[16];
#pragma unroll
    for (int k = 0; k < 16; ++k) e[k] = pvedge[min(j + k, last)];
#pragma unroll
    for (int k = 0; k < 4; ++k) {
      int ex = (q == 0) ? e[4 * k].x
                        : (q == 1) ? e[4 * k + 1].x
                                   : (q == 2) ? e[4 * k + 2].x : e[4 * k + 3].x;
      int ey = (q == 0) ? e[4 * k].y
                        : (q == 1) ? e[4 * k + 1].y
                                   : (q == 2) ? e[4 * k + 2].y : e[4 * k + 3].y;
      const __half2* p =
          reinterpret_cast<const __half2*>(htb + ((unsigned)ex + dOff));
      __half2 h0 = p[0], h1 = p[1];
      float v = (j + 4 * k + q < end) ? __int_as_float(ey) : 0.0f;
      a[0] = fmaf(v, __half2float(__low2half(h0)), a[0]);
      a[1] = fmaf(v, __half2float(__high2half(h0)), a[1]);
      a[2] = fmaf(v, __half2float(__low2half(h1)), a[2]);
      a[3] = fmaf(v, __half2float(__high2half(h1)), a[3]);
    }
  }
  // merge the 4 quarters (edge groups) -> full row partials per 16-lane group
#pragma unroll
  for (int c = 0; c < 4; ++c) {
    a[c] += __shfl_xor(a[c], 16, 64);
    a[c] += __shfl_xor(a[c], 32, 64);
  }
}

// ---- layer-1: gather SpMM + identity postagg -------------------------------
__global__ __launch_bounds__(256) void k_spmm_post(
    const __half* __restrict__ ht4, const int* __restrict__ rp4,
    const int2* __restrict__ pvedge, float* __restrict__ out4,
    float* __restrict__ aux4, int N) {
  int wave = threadIdx.x >> 6, lane = threadIdx.x & 63;
  int q = lane >> 4, d = lane & 15;
  int row = blockIdx.x * 4 + wave;
  if (row >= N) return;
  int b = blockIdx.y;
  size_t R = (size_t)b * N + row;
  const char* htb = (const char*)(ht4 + (size_t)b * N * 64);
  int beg = __builtin_amdgcn_readfirstlane(rp4[R]);
  int end = __builtin_amdgcn_readfirstlane(rp4[R + 1]);
  float a[4];
  gather_row_q4(htb, pvedge, beg, end, q, d, a);
  float ss = a[0] * a[0] + a[1] * a[1] + a[2] * a[2] + a[3] * a[3];
  float an = fmaxf(sqrtf(qsum16(ss)), 1e-30f);
  float s1 = an > kArtMaxF ? kArtMaxF / an : 1.0f;
  float t0 = fmaxf(a[0] * s1, 0.0f), t1 = fmaxf(a[1] * s1, 0.0f);
  float t2 = fmaxf(a[2] * s1, 0.0f), t3 = fmaxf(a[3] * s1, 0.0f);
  float ts = t0 * t0 + t1 * t1 + t2 * t2 + t3 * t3;
  float tn = fmaxf(sqrtf(qsum16(ts)), 1e-30f);
  float h2n = tanh_pos(tn);
  float sc = fminf(h2n, kMaxNormF) / tn;   // expmap0 + proj
  if (q == 0) {
    *reinterpret_cast<float4*>(&out4[R * 64 + d * 4]) =
        make_float4(t0 * sc, t1 * sc, t2 * sc, t3 * sc);
    if (d == 0) aux4[R] = fminf(tn, kArtMaxF);  // artanh(|h2|) exactly
  }
}

// ---- layer-2: SpMM + postagg + COMBINE fused; block=row, wave=branch -------
__global__ __launch_bounds__(256) void k_spmm_comb(
    const __half* __restrict__ ht4, const int* __restrict__ rp4,
    const int2* __restrict__ pvedge, float* __restrict__ out, int N) {
  __shared__ float lf[4][64];
  __shared__ float latn[4], lnb[4];
  int b = threadIdx.x >> 6, lane = threadIdx.x & 63;
  int q = lane >> 4, d = lane & 15;
  int row = blockIdx.x;
  size_t R = (size_t)b * N + row;
  const char* htb = (const char*)(ht4 + (size_t)b * N * 64);
  int beg = __builtin_amdgcn_readfirstlane(rp4[R]);
  int end = __builtin_amdgcn_readfirstlane(rp4[R + 1]);
  float a[4];
  gather_row_q4(htb, pvedge, beg, end, q, d, a);
  float ss = a[0] * a[0] + a[1] * a[1] + a[2] * a[2] + a[3] * a[3];
  float an = fmaxf(sqrtf(qsum16(ss)), 1e-30f);
  float s1 = an > kArtMaxF ? kArtMaxF / an : 1.0f;
  float t0 = fmaxf(a[0] * s1, 0.0f), t1 = fmaxf(a[1] * s1, 0.0f);
  float t2 = fmaxf(a[2] * s1, 0.0f), t3 = fmaxf(a[3] * s1, 0.0f);
  float ts = t0 * t0 + t1 * t1 + t2 * t2 + t3 * t3;
  float tn = fmaxf(sqrtf(qsum16(ts)), 1e-30f);
  float h2n = tanh_pos(tn);
  float nb = fminf(h2n, kMaxNormF);
  float sc = nb / tn;
  if (q == 0)
    *reinterpret_cast<float4*>(&lf[b][d * 4]) =
        make_float4(t0 * sc, t1 * sc, t2 * sc, t3 * sc);
  if (lane == 0) {
    latn[b] = fminf(tn, kArtMaxF);
    lnb[b] = fmaxf(nb, 1e-30f);
  }
  __syncthreads();
  if (b != 0) return;
  // combine (single wave): mulscaler(1/8) -> mobius chain -> mean logmap0
  float f[4], art[4], nbv[4], w[4], wn2[4], omw[4];
#pragma unroll
  for (int i = 0; i < 4; i++) {
    f[i] = lf[i][lane];
    art[i] = latn[i];
    nbv[i] = lnb[i];
    float wn = tanh_pos(art[i] * 0.125f);
    w[i] = (wn / nbv[i]) * f[i];
    wn2[i] = wn * wn;
    omw[i] = 1.0f - wn2[i];
  }
  float tgt = w[0], tx2 = wn2[0], omt = omw[0];
#pragma unroll
  for (int i = 1; i < 4; i++) {
    float xy = wsum32f(tgt * w[i]);
    float A = 1.f + 2.f * xy + wn2[i];
    float den = fmaxf(1.f + 2.f * xy + tx2 * wn2[i], 1e-15f);
    float rden = 1.0f / den;
    tgt = (A * tgt + omt * w[i]) * rden;
    omt = omt * omw[i] * rden;               // 1-|tgt|^2, stable
    tx2 = 1.0f - omt;
  }
  float tnc = fmaxf(sqrtf(fmaxf(tx2, 0.0f)), 1e-30f);
  float artt = 0.5f * __logf((1.f + tnc) * (1.f + tnc) / fmaxf(omt, 1e-30f));
  float m = (artt / tnc) * tgt;
#pragma unroll
  for (int i = 0; i < 4; i++) m += (art[i] / nbv[i]) * f[i];
  m *= 0.2f;
  float mn = fmaxf(sqrtf(wsum32f(m * m)), 1e-30f);
  float on = tanh_pos(mn);
  float pf = on > kMaxNormF ? kMaxNormF / on : 1.f;
  out[(size_t)row * 64 + lane] = m * (on / mn) * pf;
}

// ---------------------------------------------------------------------------
extern "C" void kernel_launch(void* const* d_in, const int* in_sizes, int n_in,
                              void* d_out, int out_size, void* d_ws,
                              size_t ws_size, hipStream_t stream) {
  const int FIN = 256, NB = 4;
  const int N = in_sizes[0] / FIN;       // 50000
  const int E = in_sizes[5] / NB;        // 800000
  const float* x = (const float*)d_in[0];
  const float* W1 = (const float*)d_in[1];
  const float* b1 = (const float*)d_in[2];
  const float* W2 = (const float*)d_in[3];
  const float* b2 = (const float*)d_in[4];
  const float* vals = (const float*)d_in[5];
  const int* src = (const int*)d_in[6];
  const int* dst = (const int*)d_in[7];
  float* out = (float*)d_out;
  const int n4 = NB * N;
  const int nbuck = (N + 127) >> 7;      // 391
  const int TB = NB * nbuck;

  char* w = (char*)d_ws;
  auto alloc = [&](size_t bytes) -> char* {
    char* p = w;
    w += (bytes + 255) & ~size_t(255);
    return p;
  };
  const int WF1 = NB * (FIN / 32) * 4 * 64 * 8;   // 65536 ushorts
  const int WF2 = NB * (64 / 32) * 4 * 64 * 8;    // 16384 ushorts
  unsigned short* Wf1h = (unsigned short*)alloc((size_t)WF1 * 2);
  unsigned short* Wf1l = (unsigned short*)alloc((size_t)WF1 * 2);
  unsigned short* Wf2h = (unsigned short*)alloc((size_t)WF2 * 2);
  unsigned short* Wf2l = (unsigned short*)alloc((size_t)WF2 * 2);
  float* hb1 = (float*)alloc(NB * 64 * 4);
  float* hb2 = (float*)alloc(NB * 64 * 4);
  float* y21 = (float*)alloc(NB * 4);
  float* y22 = (float*)alloc(NB * 4);
  float* omy1 = (float*)alloc(NB * 4);
  float* omy2 = (float*)alloc(NB * 4);
  float* auxT4 = (float*)alloc((size_t)n4 * 4);
  __half* Cb4 = (__half*)alloc((size_t)n4 * 64 * 2);   // f16 ht table
  float* A4 = (float*)alloc((size_t)n4 * 64 * 4);      // spmm out (f32)
  int* bcnt = (int*)alloc((size_t)TB * 4);
  int* boff = (int*)alloc(((size_t)TB + 1) * 4);
  int* bcur = (int*)alloc((size_t)TB * 4);
  int* rp4 = (int*)alloc(((size_t)n4 + 1) * 4);
  int2* pvedge = (int2*)alloc((size_t)NB * E * 8);
  // ebuf aliases Cb4 (dead until k_gemm1; both exactly 25.6MB)
  int2* ebuf = (int2*)Cb4;

  const int rowBlocks = (N + 3) / 4;
  const int g1Blocks = (N + 15) / 16;      // 3125: 16 rows/block, wave=branch
  const int g2Blocks = (N + 63) / 64;
  const int hBlocks = (E + 8191) / 8192;   // 98

  k_wprep<<<(WF1 / 8 + 255) / 256, 256, 0, stream>>>(W1, Wf1h, Wf1l, FIN, WF1 / 8);
  k_wprep<<<(WF2 / 8 + 255) / 256, 256, 0, stream>>>(W2, Wf2h, Wf2l, 64, WF2 / 8);
  k_bias<<<1, 512, 0, stream>>>(b1, b2, hb1, hb2, y21, y22, omy1, omy2);

  // ---- CSR build: bucketed counting sort over all 4 branches ----
  hipMemsetAsync(bcnt, 0, (size_t)TB * 4, stream);
  k_bhist<<<dim3(hBlocks, NB), 512, 0, stream>>>(dst, bcnt, E, nbuck);
  k_bscan<<<1, 256, 0, stream>>>(bcnt, boff, bcur, rp4, TB, n4, NB * E);
  k_bpart<<<dim3(hBlocks, NB), 512, 0, stream>>>(src, dst, vals, bcur, ebuf, E, nbuck);
  k_bfine<<<dim3(nbuck, NB), 256, 0, stream>>>(ebuf, boff, rp4, pvedge, N, nbuck);

  // ---- layer 1: GEMM(+tail fused) then SpMM(+postagg) ----
  k_gemm1<<<g1Blocks, 256, 0, stream>>>(x, Wf1h, Wf1l, Cb4, hb1, y21, omy1, N);
  k_spmm_post<<<dim3(rowBlocks, NB), 256, 0, stream>>>(Cb4, rp4, pvedge, A4,
                                                       auxT4, N);
  // ---- layer 2: GEMM(+tail fused) then SpMM+combine fused ----
  k_gemm2<<<dim3(g2Blocks, NB), 256, 0, stream>>>(A4, Wf2h, Wf2l, Cb4, auxT4,
                                                  hb2, y22, omy2, N);
  k_spmm_comb<<<N, 256, 0, stream>>>(Cb4, rp4, pvedge, out, N);
}

// Round 14
// 381.627 us; speedup vs baseline: 1.4405x; 1.4405x over previous
//
#include <hip/hip_runtime.h>
#include <hip/hip_fp16.h>
#include <math.h>

// ---------------------------------------------------------------------------
// DHYPR hyperbolic GNN encoder, MI355X (gfx950).  Round 14 = round 12 revert
// (round 13's quad-gather spilled to scratch: WRITE_SIZE 12.5MB -> 728MB).
// Structure: MFMA bf16-split GEMMs with fused f32 gyro-stable Mobius tails;
// bucketed counting-sort CSR; f16 gather tables; 16-edge-chunk paired gather
// (scalar records, 2 rows per VMEM instr); layer-2 SpMM fused with combine.
// ---------------------------------------------------------------------------

constexpr double kMaxNorm = 1.0 - 1e-5;   // (1-PROJ_EPS)/sqrt(c), c=1
constexpr double kMinNorm = 1e-15;
#define kMaxNormF 0.99999f
#define kArtMaxF  6.1030338f
#define kOmMaxF   1.99999e-5f                    // 1 - kMaxNorm^2

typedef __attribute__((ext_vector_type(8))) short short8v;   // 8 bf16
typedef __attribute__((ext_vector_type(4))) float f32x4;

__device__ inline double wsum64(double v) {
#pragma unroll
  for (int o = 32; o > 0; o >>= 1) v += __shfl_xor(v, o, 64);
  return v;
}
__device__ inline float wsum32f(float v) {
#pragma unroll
  for (int o = 32; o > 0; o >>= 1) v += __shfl_xor(v, o, 64);
  return v;
}
__device__ inline float wsum32h(float v) {  // sum within each 32-lane half
#pragma unroll
  for (int o = 1; o < 32; o <<= 1) v += __shfl_xor(v, o, 64);
  return v;
}
__device__ inline float qsum16(float v) {   // reduce within 16-lane group
#pragma unroll
  for (int o = 1; o < 16; o <<= 1) v += __shfl_xor(v, o, 64);
  return v;
}
__device__ inline float tanh_pos(float z) {  // z >= 0, cancellation-free
  float e = __expf(-2.0f * z);
  return (1.0f - e) / (1.0f + e);
}

__device__ inline unsigned short f2bf(float f) {  // RN-even f32->bf16
  union { float f; unsigned int u; } v{f};
  unsigned int r = v.u + 0x7fffu + ((v.u >> 16) & 1u);
  return (unsigned short)(r >> 16);
}
__device__ inline float bf2f(unsigned short h) {
  union { unsigned int u; float f; } v{(unsigned int)h << 16};
  return v.f;
}

// ---- hb = proj(expmap0(bias)) ; outputs f32 (+ y2, 1-y2 scalars) -----------
__global__ __launch_bounds__(512) void k_bias(const float* __restrict__ b1,
                                              const float* __restrict__ b2,
                                              float* __restrict__ hb1,
                                              float* __restrict__ hb2,
                                              float* __restrict__ y21,
                                              float* __restrict__ y22,
                                              float* __restrict__ omy1,
                                              float* __restrict__ omy2) {
  int w = threadIdx.x >> 6, lane = threadIdx.x & 63;
  const float* bs = (w < 4) ? (b1 + w * 64) : (b2 + (w - 4) * 64);
  double v = (double)bs[lane];
  double un = fmax(sqrt(wsum64(v * v)), kMinNorm);
  double pn = tanh(un);
  double pf = pn > kMaxNorm ? kMaxNorm / pn : 1.0;
  double p = v * (pn / un) * pf;
  float* hb = (w < 4) ? hb1 + w * 64 : hb2 + (w - 4) * 64;
  hb[lane] = (float)p;
  if (lane == 0) {
    double n = pn * pf;
    int i = (w < 4) ? w : w - 4;
    float* y2 = (w < 4) ? y21 : y22;
    float* omy = (w < 4) ? omy1 : omy2;
    y2[i] = (float)(n * n);
    omy[i] = (float)(1.0 - n * n);
  }
}

// ---- weight prep: fragment-ready bf16 hi/lo, layout [s][b][f][lane][8] -----
__global__ __launch_bounds__(256) void k_wprep(const float* __restrict__ W,
                                               unsigned short* __restrict__ Wfh,
                                               unsigned short* __restrict__ Wfl,
                                               int DIN, int tot) {
  int idx = blockIdx.x * 256 + threadIdx.x;
  if (idx >= tot) return;
  int lane = idx & 63;
  int t = idx >> 6;
  int f = t & 3; t >>= 2;
  int ks = DIN >> 5;
  int s = t % ks;
  int b = t / ks;
  int c = f * 16 + (lane & 15);
  int k = s * 32 + (lane >> 4) * 8;
  const float* wp = W + ((size_t)(b * 64 + c)) * DIN + k;
  size_t dst = (((size_t)(s * 4 + b) * 4 + f) * 64 + lane) * 8;
#pragma unroll
  for (int j = 0; j < 8; ++j) {
    float v = wp[j];
    unsigned short h = f2bf(v);
    unsigned short l = f2bf(v - bf2f(h));
    Wfh[dst + j] = h;
    Wfl[dst + j] = l;
  }
}

// ---- shared epilogue: full Mobius tail for one row-chain -------------------
__device__ inline void tail_chain(float mx[4], float sart_row,
                                  const float hbv[4], float y2, float omy) {
  float p = mx[0] * mx[0] + mx[1] * mx[1] + mx[2] * mx[2] + mx[3] * mx[3];
  float mxn = fmaxf(sqrtf(qsum16(p)), 1e-30f);
  float z = mxn * sart_row;
  float e = __expf(-2.0f * z);
  float r1 = 1.0f / (1.0f + e);
  float nmv = (1.0f - e) * r1;
  float om = 4.0f * e * r1 * r1;
  float pf1 = nmv > kMaxNormF ? kMaxNormF / nmv : 1.0f;   // proj
  float nmvc = nmv * pf1;
  float x2 = nmvc * nmvc;
  float omx = (pf1 < 1.0f) ? kOmMaxF : om;                // 1 - x2, stable
  float mvs = nmvc / mxn;
  float pxy = 0.0f;
#pragma unroll
  for (int f = 0; f < 4; ++f) {
    mx[f] = mvs * mx[f];
    pxy += mx[f] * hbv[f];
  }
  float xy = qsum16(pxy);
  float A = 1.0f + 2.0f * xy + y2;
  float den = fmaxf(1.0f + 2.0f * xy + x2 * y2, 1e-15f);
  float rden = 1.0f / den;
  float hn2 = (x2 + 2.0f * xy + y2) * rden;
  float omh = omx * omy * rden;                           // 1 - hn^2
  float hn = fmaxf(sqrtf(fmaxf(hn2, 0.0f)), 1e-30f);
  float pf2 = 1.0f;
  if (hn > kMaxNormF) {                                   // proj
    pf2 = kMaxNormF / hn;
    hn = kMaxNormF;
    omh = kOmMaxF;
  }
  float art = 0.5f * __logf((1.0f + hn) * (1.0f + hn) / omh);
  float hts = (art / hn) * pf2 * rden;
#pragma unroll
  for (int f = 0; f < 4; ++f)
    mx[f] = hts * (A * mx[f] + omx * hbv[f]);
}

// ---- layer-1 GEMM + prescale + FUSED tail; block = 16 rows, wave = branch --
__global__ __launch_bounds__(256) void k_gemm1(const float* __restrict__ X,
                                               const unsigned short* __restrict__ Wfh,
                                               const unsigned short* __restrict__ Wfl,
                                               __half* __restrict__ C4,
                                               const float* __restrict__ hbAll,
                                               const float* __restrict__ y2All,
                                               const float* __restrict__ omyAll,
                                               int N) {
  const int bb = threadIdx.x >> 6, lane = threadIdx.x & 63;
  const int r0 = blockIdx.x * 16;
  const int l = lane & 15, g = lane >> 4;
  const int arow = min(r0 + l, N - 1);
  const int kbase = g * 8;
  f32x4 acc[4] = {};
  double ss = 0.0;
#pragma unroll
  for (int s = 0; s < 8; ++s) {
    const float* ap = X + (size_t)arow * 256 + s * 32 + kbase;
    const float4 a0 = *reinterpret_cast<const float4*>(ap);
    const float4 a1 = *reinterpret_cast<const float4*>(ap + 4);
    float av[8] = {a0.x, a0.y, a0.z, a0.w, a1.x, a1.y, a1.z, a1.w};
    short8v ah, al;
#pragma unroll
    for (int j = 0; j < 8; ++j) {
      ss += (double)av[j] * av[j];
      unsigned short h = f2bf(av[j]);
      ah[j] = (short)h;
      al[j] = (short)f2bf(av[j] - bf2f(h));
    }
#pragma unroll
    for (int f = 0; f < 4; ++f) {
      size_t wi = (((size_t)(s * 4 + bb) * 4 + f) * 64 + lane) * 8;
      short8v bh = *reinterpret_cast<const short8v*>(Wfh + wi);
      short8v bl = *reinterpret_cast<const short8v*>(Wfl + wi);
      acc[f] = __builtin_amdgcn_mfma_f32_16x16x32_bf16(ah, bl, acc[f], 0, 0, 0);
      acc[f] = __builtin_amdgcn_mfma_f32_16x16x32_bf16(al, bh, acc[f], 0, 0, 0);
      acc[f] = __builtin_amdgcn_mfma_f32_16x16x32_bf16(ah, bh, acc[f], 0, 0, 0);
    }
  }
  // prescale for input row r0+l (expmap0(x) scale + artanh factor)
  ss += __shfl_xor(ss, 16, 64);
  ss += __shfl_xor(ss, 32, 64);
  float un = fmaxf(sqrtf((float)ss), 1e-30f);
  float pn = tanh_pos(un);
  float pfx = pn > kMaxNormF ? kMaxNormF / pn : 1.0f;
  float xn = fmaxf(pn * pfx, 1e-30f);
  float s_i = (pn / un) * pfx;
  float sart_i = fminf(un, kArtMaxF) / xn;   // artanh(xn)/xn exactly
  float hbv[4];
  float y2v = y2All[bb], omyv = omyAll[bb];
#pragma unroll
  for (int f = 0; f < 4; ++f) hbv[f] = hbAll[bb * 64 + f * 16 + l];
#pragma unroll
  for (int j = 0; j < 4; ++j) {
    int row = r0 + g * 4 + j;
    float s_row = __shfl(s_i, g * 4 + j, 64);
    float sart_row = __shfl(sart_i, g * 4 + j, 64);
    float mx[4] = {s_row * acc[0][j], s_row * acc[1][j], s_row * acc[2][j],
                   s_row * acc[3][j]};
    tail_chain(mx, sart_row, hbv, y2v, omyv);
    if (row < N) {
      size_t base = ((size_t)bb * N + row) * 64 + l;
      C4[base] = __float2half(mx[0]);
      C4[base + 16] = __float2half(mx[1]);
      C4[base + 32] = __float2half(mx[2]);
      C4[base + 48] = __float2half(mx[3]);
    }
  }
}

// ---- layer-2 GEMM + FUSED tail: per-branch (blockIdx.y), DIN=64 ------------
__global__ __launch_bounds__(256) void k_gemm2(const float* __restrict__ X4,
                                               const unsigned short* __restrict__ Wfh,
                                               const unsigned short* __restrict__ Wfl,
                                               __half* __restrict__ C4,
                                               const float* __restrict__ auxT4,
                                               const float* __restrict__ hbAll,
                                               const float* __restrict__ y2All,
                                               const float* __restrict__ omyAll,
                                               int N) {
  const int wave = threadIdx.x >> 6, lane = threadIdx.x & 63;
  const int b = blockIdx.y;
  const int r0 = blockIdx.x * 64 + wave * 16;
  const int l = lane & 15, g = lane >> 4;
  const int arow = min(r0 + l, N - 1);
  const int kbase = g * 8;
  const float* X = X4 + (size_t)b * N * 64;
  f32x4 acc[4] = {};
#pragma unroll
  for (int s = 0; s < 2; ++s) {
    const float* ap = X + (size_t)arow * 64 + s * 32 + kbase;
    const float4 a0 = *reinterpret_cast<const float4*>(ap);
    const float4 a1 = *reinterpret_cast<const float4*>(ap + 4);
    float av[8] = {a0.x, a0.y, a0.z, a0.w, a1.x, a1.y, a1.z, a1.w};
    short8v ah, al;
#pragma unroll
    for (int j = 0; j < 8; ++j) {
      unsigned short h = f2bf(av[j]);
      ah[j] = (short)h;
      al[j] = (short)f2bf(av[j] - bf2f(h));
    }
#pragma unroll
    for (int f = 0; f < 4; ++f) {
      size_t wi = (((size_t)(s * 4 + b) * 4 + f) * 64 + lane) * 8;
      short8v bh = *reinterpret_cast<const short8v*>(Wfh + wi);
      short8v bl = *reinterpret_cast<const short8v*>(Wfl + wi);
      acc[f] = __builtin_amdgcn_mfma_f32_16x16x32_bf16(ah, bl, acc[f], 0, 0, 0);
      acc[f] = __builtin_amdgcn_mfma_f32_16x16x32_bf16(al, bh, acc[f], 0, 0, 0);
      acc[f] = __builtin_amdgcn_mfma_f32_16x16x32_bf16(ah, bh, acc[f], 0, 0, 0);
    }
  }
  float atn = auxT4[(size_t)b * N + arow];
  float xn = fmaxf(tanh_pos(atn), 1e-30f);
  float sart_i = atn / xn;
  float hbv[4];
  float y2v = y2All[b], omyv = omyAll[b];
#pragma unroll
  for (int f = 0; f < 4; ++f) hbv[f] = hbAll[b * 64 + f * 16 + l];
#pragma unroll
  for (int j = 0; j < 4; ++j) {
    int row = r0 + g * 4 + j;
    float sart_row = __shfl(sart_i, g * 4 + j, 64);
    float mx[4] = {acc[0][j], acc[1][j], acc[2][j], acc[3][j]};
    tail_chain(mx, sart_row, hbv, y2v, omyv);
    if (row < N) {
      size_t base = ((size_t)b * N + row) * 64 + l;
      C4[base] = __float2half(mx[0]);
      C4[base + 16] = __float2half(mx[1]);
      C4[base + 32] = __float2half(mx[2]);
      C4[base + 48] = __float2half(mx[3]);
    }
  }
}

// ===================== CSR build: bucketed counting sort ====================
__global__ __launch_bounds__(512) void k_bhist(const int* __restrict__ dst,
                                               int* __restrict__ bcnt, int E,
                                               int nbuck) {
  __shared__ int lcnt[512];
  int tid = threadIdx.x;
  for (int k = tid; k < nbuck; k += 512) lcnt[k] = 0;
  __syncthreads();
  int b = blockIdx.y;
  int e0 = blockIdx.x * 8192;
  const int* db = dst + (size_t)b * E;
#pragma unroll
  for (int i = 0; i < 16; ++i) {
    int e = e0 + i * 512 + tid;
    if (e < E) atomicAdd(&lcnt[db[e] >> 7], 1);
  }
  __syncthreads();
  for (int k = tid; k < nbuck; k += 512) {
    int c = lcnt[k];
    if (c) atomicAdd(&bcnt[b * nbuck + k], c);
  }
}

__global__ __launch_bounds__(256) void k_bscan(const int* __restrict__ bcnt,
                                               int* __restrict__ boff,
                                               int* __restrict__ bcur,
                                               int* __restrict__ rp4, int TB,
                                               int n4, int Etot) {
  __shared__ int wsums[4];
  int t = threadIdx.x;
  int lane = t & 63, wv = t >> 6;
  int vals[8];
  int s = 0;
#pragma unroll
  for (int i = 0; i < 8; ++i) {
    int idx = t * 8 + i;
    int v = (idx < TB) ? bcnt[idx] : 0;
    vals[i] = s;
    s += v;
  }
  int incl = s;
#pragma unroll
  for (int o = 1; o < 64; o <<= 1) {
    int u = __shfl_up(incl, o, 64);
    if (lane >= o) incl += u;
  }
  if (lane == 63) wsums[wv] = incl;
  __syncthreads();
  int woff = 0;
  for (int i = 0; i < wv; ++i) woff += wsums[i];
  int texcl = woff + incl - s;
#pragma unroll
  for (int i = 0; i < 8; ++i) {
    int idx = t * 8 + i;
    if (idx < TB) {
      int o = texcl + vals[i];
      boff[idx] = o;
      bcur[idx] = o;
    }
  }
  if (t == 0) {
    boff[TB] = Etot;
    rp4[n4] = Etot;
  }
}

__global__ __launch_bounds__(512) void k_bpart(const int* __restrict__ src,
                                               const int* __restrict__ dst,
                                               const float* __restrict__ val,
                                               int* __restrict__ bcur,
                                               int2* __restrict__ ebuf, int E,
                                               int nbuck) {
  __shared__ int lcnt[512];
  __shared__ int lbase[512];
  int tid = threadIdx.x;
  for (int k = tid; k < nbuck; k += 512) lcnt[k] = 0;
  __syncthreads();
  int b = blockIdx.y;
  int e0 = blockIdx.x * 8192;
  const int* db = dst + (size_t)b * E;
  const int* sb = src + (size_t)b * E;
  const float* vb = val + (size_t)b * E;
#pragma unroll
  for (int i = 0; i < 16; ++i) {
    int e = e0 + i * 512 + tid;
    if (e < E) atomicAdd(&lcnt[db[e] >> 7], 1);
  }
  __syncthreads();
  for (int k = tid; k < nbuck; k += 512) {
    int c = lcnt[k];
    lbase[k] = c ? atomicAdd(&bcur[b * nbuck + k], c) : 0;
  }
  __syncthreads();
  for (int k = tid; k < nbuck; k += 512) lcnt[k] = 0;
  __syncthreads();
#pragma unroll
  for (int i = 0; i < 16; ++i) {
    int e = e0 + i * 512 + tid;
    if (e < E) {
      int d = db[e];
      int bk = d >> 7;
      int r = atomicAdd(&lcnt[bk], 1);
      int2 ev;
      ev.x = ((d & 127) << 17) | sb[e];
      ev.y = __float_as_int(vb[e]);
      ebuf[(size_t)lbase[bk] + r] = ev;
    }
  }
}

__global__ __launch_bounds__(256) void k_bfine(const int2* __restrict__ ebuf,
                                               const int* __restrict__ boff,
                                               int* __restrict__ rp4,
                                               int2* __restrict__ pvedge,
                                               int N, int nbuck) {
  __shared__ int ncnt[128], noff[128], ncur[128];
  __shared__ int w0tot;
  int tid = threadIdx.x;
  int br = blockIdx.y, bk = blockIdx.x;
  int idx = br * nbuck + bk;
  int ebeg = boff[idx], eend = boff[idx + 1];
  int n0 = bk << 7;
  int nn = min(128, N - n0);
  if (tid < 128) ncnt[tid] = 0;
  __syncthreads();
  for (int j = ebeg + tid; j < eend; j += 256)
    atomicAdd(&ncnt[ebuf[j].x >> 17], 1);
  __syncthreads();
  int v = (tid < 128) ? ncnt[tid] : 0;
  int lane = tid & 63;
  int incl = v;
#pragma unroll
  for (int o = 1; o < 64; o <<= 1) {
    int u = __shfl_up(incl, o, 64);
    if (lane >= o) incl += u;
  }
  if (tid == 63) w0tot = incl;
  __syncthreads();
  if (tid >= 64 && tid < 128) incl += w0tot;
  if (tid < 128) {
    noff[tid] = incl - v;
    ncur[tid] = incl - v;
  }
  __syncthreads();
  if (tid < nn) rp4[(size_t)br * N + n0 + tid] = ebeg + noff[tid];
  for (int j = ebeg + tid; j < eend; j += 256) {
    int2 ev = ebuf[j];
    int dl = ev.x >> 17;
    int pos = ebeg + atomicAdd(&ncur[dl], 1);
    // .x = src*128: byte offset of the f16 row (row = 64 halves = 128 B)
    pvedge[pos] = make_int2((ev.x & 0x1FFFF) << 7, ev.y);
  }
}

// ---- paired f16 gather, 16-edge chunks, records read upfront ---------------
// htb = branch table base; edge .x = src*128 byte offset. Lanes 0-31 take
// even edges, 32-63 odd. One lgkm wait + one vmcnt region per chunk.
__device__ inline float2 gather_row16(const char* __restrict__ htb,
                                      const int2* __restrict__ pvedge,
                                      int beg, int end, int half, int sub) {
  float ax = 0.0f, ay = 0.0f;
  const unsigned subOff = (unsigned)sub * 4u;
  int j = beg;
  for (; j + 16 <= end; j += 16) {
    int2 e[16];
#pragma unroll
    for (int k = 0; k < 16; ++k) e[k] = pvedge[j + k];
#pragma unroll
    for (int k = 0; k < 8; ++k) {
      int2 eh = half ? e[2 * k + 1] : e[2 * k];
      __half2 h =
          *reinterpret_cast<const __half2*>(htb + ((unsigned)eh.x + subOff));
      float v = __int_as_float(eh.y);
      ax = fmaf(v, __half2float(__low2half(h)), ax);
      ay = fmaf(v, __half2float(__high2half(h)), ay);
    }
  }
  if (j < end) {  // clamped+masked final chunk (dummy gathers hit last row)
    int last = end - 1;
    int2 e[16];
#pragma unroll
    for (int k = 0; k < 16; ++k) e[k] = pvedge[min(j + k, last)];
#pragma unroll
    for (int k = 0; k < 8; ++k) {
      int idx = 2 * k + half;
      int2 eh = half ? e[2 * k + 1] : e[2 * k];
      __half2 h =
          *reinterpret_cast<const __half2*>(htb + ((unsigned)eh.x + subOff));
      float v = (j + idx < end) ? __int_as_float(eh.y) : 0.0f;
      ax = fmaf(v, __half2float(__low2half(h)), ax);
      ay = fmaf(v, __half2float(__high2half(h)), ay);
    }
  }
  ax += __shfl_xor(ax, 32, 64);
  ay += __shfl_xor(ay, 32, 64);
  return make_float2(ax, ay);
}

// ---- layer-1: gather SpMM + identity postagg -------------------------------
__global__ __launch_bounds__(256) void k_spmm_post(
    const __half* __restrict__ ht4, const int* __restrict__ rp4,
    const int2* __restrict__ pvedge, float* __restrict__ out4,
    float* __restrict__ aux4, int N) {
  int wave = threadIdx.x >> 6, lane = threadIdx.x & 63;
  int half = lane >> 5, sub = lane & 31;
  int row = blockIdx.x * 4 + wave;
  if (row >= N) return;
  int b = blockIdx.y;
  size_t R = (size_t)b * N + row;
  const char* htb = (const char*)(ht4 + (size_t)b * N * 64);
  int beg = __builtin_amdgcn_readfirstlane(rp4[R]);
  int end = __builtin_amdgcn_readfirstlane(rp4[R + 1]);
  float2 acc = gather_row16(htb, pvedge, beg, end, half, sub);
  float an = fmaxf(sqrtf(wsum32h(acc.x * acc.x + acc.y * acc.y)), 1e-30f);
  float s1 = an > kArtMaxF ? kArtMaxF / an : 1.0f;
  float tx = fmaxf(acc.x * s1, 0.0f), ty = fmaxf(acc.y * s1, 0.0f);
  float tn = fmaxf(sqrtf(wsum32h(tx * tx + ty * ty)), 1e-30f);
  float h2n = tanh_pos(tn);
  float sc = fminf(h2n, kMaxNormF) / tn;   // expmap0 + proj
  if (half == 0) {
    *reinterpret_cast<float2*>(&out4[R * 64 + sub * 2]) =
        make_float2(tx * sc, ty * sc);
    if (sub == 0) aux4[R] = fminf(tn, kArtMaxF);  // artanh(|h2|) exactly
  }
}

// ---- layer-2: SpMM + postagg + COMBINE fused; block=row, wave=branch -------
__global__ __launch_bounds__(256) void k_spmm_comb(
    const __half* __restrict__ ht4, const int* __restrict__ rp4,
    const int2* __restrict__ pvedge, float* __restrict__ out, int N) {
  __shared__ float lf[4][64];
  __shared__ float latn[4], lnb[4];
  int b = threadIdx.x >> 6, lane = threadIdx.x & 63;
  int half = lane >> 5, sub = lane & 31;
  int row = blockIdx.x;
  size_t R = (size_t)b * N + row;
  const char* htb = (const char*)(ht4 + (size_t)b * N * 64);
  int beg = __builtin_amdgcn_readfirstlane(rp4[R]);
  int end = __builtin_amdgcn_readfirstlane(rp4[R + 1]);
  float2 acc = gather_row16(htb, pvedge, beg, end, half, sub);
  float an = fmaxf(sqrtf(wsum32h(acc.x * acc.x + acc.y * acc.y)), 1e-30f);
  float s1 = an > kArtMaxF ? kArtMaxF / an : 1.0f;
  float tx = fmaxf(acc.x * s1, 0.0f), ty = fmaxf(acc.y * s1, 0.0f);
  float tn = fmaxf(sqrtf(wsum32h(tx * tx + ty * ty)), 1e-30f);
  float h2n = tanh_pos(tn);
  float nb = fminf(h2n, kMaxNormF);
  float sc = nb / tn;
  if (half == 0)
    *reinterpret_cast<float2*>(&lf[b][sub * 2]) =
        make_float2(tx * sc, ty * sc);
  if (lane == 0) {
    latn[b] = fminf(tn, kArtMaxF);
    lnb[b] = fmaxf(nb, 1e-30f);
  }
  __syncthreads();
  if (b != 0) return;
  // combine (single wave): mulscaler(1/8) -> mobius chain -> mean logmap0
  float f[4], art[4], nbv[4], w[4], wn2[4], omw[4];
#pragma unroll
  for (int i = 0; i < 4; i++) {
    f[i] = lf[i][lane];
    art[i] = latn[i];
    nbv[i] = lnb[i];
    float wn = tanh_pos(art[i] * 0.125f);
    w[i] = (wn / nbv[i]) * f[i];
    wn2[i] = wn * wn;
    omw[i] = 1.0f - wn2[i];
  }
  float tgt = w[0], tx2 = wn2[0], omt = omw[0];
#pragma unroll
  for (int i = 1; i < 4; i++) {
    float xy = wsum32f(tgt * w[i]);
    float A = 1.f + 2.f * xy + wn2[i];
    float den = fmaxf(1.f + 2.f * xy + tx2 * wn2[i], 1e-15f);
    float rden = 1.0f / den;
    tgt = (A * tgt + omt * w[i]) * rden;
    omt = omt * omw[i] * rden;               // 1-|tgt|^2, stable
    tx2 = 1.0f - omt;
  }
  float tnc = fmaxf(sqrtf(fmaxf(tx2, 0.0f)), 1e-30f);
  float artt = 0.5f * __logf((1.f + tnc) * (1.f + tnc) / fmaxf(omt, 1e-30f));
  float m = (artt / tnc) * tgt;
#pragma unroll
  for (int i = 0; i < 4; i++) m += (art[i] / nbv[i]) * f[i];
  m *= 0.2f;
  float mn = fmaxf(sqrtf(wsum32f(m * m)), 1e-30f);
  float on = tanh_pos(mn);
  float pf = on > kMaxNormF ? kMaxNormF / on : 1.f;
  out[(size_t)row * 64 + lane] = m * (on / mn) * pf;
}

// ---------------------------------------------------------------------------
extern "C" void kernel_launch(void* const* d_in, const int* in_sizes, int n_in,
                              void* d_out, int out_size, void* d_ws,
                              size_t ws_size, hipStream_t stream) {
  const int FIN = 256, NB = 4;
  const int N = in_sizes[0] / FIN;       // 50000
  const int E = in_sizes[5] / NB;        // 800000
  const float* x = (const float*)d_in[0];
  const float* W1 = (const float*)d_in[1];
  const float* b1 = (const float*)d_in[2];
  const float* W2 = (const float*)d_in[3];
  const float* b2 = (const float*)d_in[4];
  const float* vals = (const float*)d_in[5];
  const int* src = (const int*)d_in[6];
  const int* dst = (const int*)d_in[7];
  float* out = (float*)d_out;
  const int n4 = NB * N;
  const int nbuck = (N + 127) >> 7;      // 391
  const int TB = NB * nbuck;

  char* w = (char*)d_ws;
  auto alloc = [&](size_t bytes) -> char* {
    char* p = w;
    w += (bytes + 255) & ~size_t(255);
    return p;
  };
  const int WF1 = NB * (FIN / 32) * 4 * 64 * 8;   // 65536 ushorts
  const int WF2 = NB * (64 / 32) * 4 * 64 * 8;    // 16384 ushorts
  unsigned short* Wf1h = (unsigned short*)alloc((size_t)WF1 * 2);
  unsigned short* Wf1l = (unsigned short*)alloc((size_t)WF1 * 2);
  unsigned short* Wf2h = (unsigned short*)alloc((size_t)WF2 * 2);
  unsigned short* Wf2l = (unsigned short*)alloc((size_t)WF2 * 2);
  float* hb1 = (float*)alloc(NB * 64 * 4);
  float* hb2 = (float*)alloc(NB * 64 * 4);
  float* y21 = (float*)alloc(NB * 4);
  float* y22 = (float*)alloc(NB * 4);
  float* omy1 = (float*)alloc(NB * 4);
  float* omy2 = (float*)alloc(NB * 4);
  float* auxT4 = (float*)alloc((size_t)n4 * 4);
  __half* Cb4 = (__half*)alloc((size_t)n4 * 64 * 2);   // f16 ht table
  float* A4 = (float*)alloc((size_t)n4 * 64 * 4);      // spmm out (f32)
  int* bcnt = (int*)alloc((size_t)TB * 4);
  int* boff = (int*)alloc(((size_t)TB + 1) * 4);
  int* bcur = (int*)alloc((size_t)TB * 4);
  int* rp4 = (int*)alloc(((size_t)n4 + 1) * 4);
  int2* pvedge = (int2*)alloc((size_t)NB * E * 8);
  // ebuf aliases Cb4 (dead until k_gemm1; both exactly 25.6MB)
  int2* ebuf = (int2*)Cb4;

  const int rowBlocks = (N + 3) / 4;
  const int g1Blocks = (N + 15) / 16;      // 3125: 16 rows/block, wave=branch
  const int g2Blocks = (N + 63) / 64;
  const int hBlocks = (E + 8191) / 8192;   // 98

  k_wprep<<<(WF1 / 8 + 255) / 256, 256, 0, stream>>>(W1, Wf1h, Wf1l, FIN, WF1 / 8);
  k_wprep<<<(WF2 / 8 + 255) / 256, 256, 0, stream>>>(W2, Wf2h, Wf2l, 64, WF2 / 8);
  k_bias<<<1, 512, 0, stream>>>(b1, b2, hb1, hb2, y21, y22, omy1, omy2);

  // ---- CSR build: bucketed counting sort over all 4 branches ----
  hipMemsetAsync(bcnt, 0, (size_t)TB * 4, stream);
  k_bhist<<<dim3(hBlocks, NB), 512, 0, stream>>>(dst, bcnt, E, nbuck);
  k_bscan<<<1, 256, 0, stream>>>(bcnt, boff, bcur, rp4, TB, n4, NB * E);
  k_bpart<<<dim3(hBlocks, NB), 512, 0, stream>>>(src, dst, vals, bcur, ebuf, E, nbuck);
  k_bfine<<<dim3(nbuck, NB), 256, 0, stream>>>(ebuf, boff, rp4, pvedge, N, nbuck);

  // ---- layer 1: GEMM(+tail fused) then SpMM(+postagg) ----
  k_gemm1<<<g1Blocks, 256, 0, stream>>>(x, Wf1h, Wf1l, Cb4, hb1, y21, omy1, N);
  k_spmm_post<<<dim3(rowBlocks, NB), 256, 0, stream>>>(Cb4, rp4, pvedge, A4,
                                                       auxT4, N);
  // ---- layer 2: GEMM(+tail fused) then SpMM+combine fused ----
  k_gemm2<<<dim3(g2Blocks, NB), 256, 0, stream>>>(A4, Wf2h, Wf2l, Cb4, auxT4,
                                                  hb2, y22, omy2, N);
  k_spmm_comb<<<N, 256, 0, stream>>>(Cb4, rp4, pvedge, out, N);
}